// Round 1
// baseline (373.265 us; speedup 1.0000x reference)
//
#include <hip/hip_runtime.h>
#include <hip/hip_bf16.h>

#define SEQ 2048
#define DIM 1024
#define NH  16
#define HD  64

typedef __bf16 bf16_t;
typedef __bf16 bf16x4 __attribute__((ext_vector_type(4)));
typedef __bf16 bf16x8 __attribute__((ext_vector_type(8)));
typedef float  f32x4  __attribute__((ext_vector_type(4)));

#define MFMA16(a,b,c) __builtin_amdgcn_mfma_f32_16x16x32_bf16((a),(b),(c),0,0,0)

// ---------------- cos/sin tables: [2048][32] ----------------
__global__ __launch_bounds__(256) void k_tables(const float* __restrict__ invf,
                                                float* __restrict__ cosT,
                                                float* __restrict__ sinT) {
    int id = blockIdx.x * 256 + threadIdx.x;     // 65536 total
    int t = id >> 5, i = id & 31;
    float f = (float)t * invf[i];
    cosT[id] = cosf(f);
    sinT[id] = sinf(f);
}

// ---------------- f32 -> bf16 convert (x4 per thread) ----------------
__global__ __launch_bounds__(256) void k_cvt(const float* __restrict__ in,
                                             bf16_t* __restrict__ out, int n4) {
    int id = blockIdx.x * 256 + threadIdx.x;
    if (id < n4) {
        float4 v = ((const float4*)in)[id];
        bf16x4 o;
        o[0] = (bf16_t)v.x; o[1] = (bf16_t)v.y; o[2] = (bf16_t)v.z; o[3] = (bf16_t)v.w;
        ((bf16x4*)out)[id] = o;
    }
}

// ---------------- NT GEMM: C[M][N] = A[M][K] @ W[N][K]^T (+bias) ----------------
// block = 256 (4 waves); wave computes 16x64; block tile 64x64.
__global__ __launch_bounds__(256) void gemm_nt(const bf16_t* __restrict__ A,
                                               const bf16_t* __restrict__ W,
                                               const float* __restrict__ bias, int hasBias,
                                               bf16_t* __restrict__ outBf,
                                               float* __restrict__ outF,
                                               int M, int N, int K) {
    int tid = threadIdx.x, wid = tid >> 6, lane = tid & 63;
    int lrow = lane >> 4, lcol = lane & 15;
    int m0 = blockIdx.x * 64 + wid * 16;
    int n0 = blockIdx.y * 64;

    f32x4 acc[4] = {};
    const bf16_t* arow = A + (size_t)(m0 + lcol) * K + lrow * 8;
    const bf16_t* wrow = W + (size_t)(n0 + lcol) * K + lrow * 8;

#pragma unroll 2
    for (int k = 0; k < K; k += 32) {
        bf16x8 a = *(const bf16x8*)(arow + k);
#pragma unroll
        for (int ng = 0; ng < 4; ng++) {
            bf16x8 b = *(const bf16x8*)(wrow + (size_t)ng * 16 * K + k);
            acc[ng] = MFMA16(a, b, acc[ng]);
        }
    }
#pragma unroll
    for (int ng = 0; ng < 4; ng++) {
        int col = n0 + ng * 16 + lcol;
        float bb = hasBias ? bias[col] : 0.0f;
#pragma unroll
        for (int j = 0; j < 4; j++) {
            int row = m0 + lrow * 4 + j;
            float v = acc[ng][j] + bb;
            if (outBf) outBf[(size_t)row * N + col] = (bf16_t)v;
            else       outF [(size_t)row * N + col] = v;
        }
    }
}

// ---------------- RoPE + scale for Q,K; token_ids from rotated K[...,0] ----------------
__global__ __launch_bounds__(256) void k_rope(const bf16_t* __restrict__ Qraw,
                                              const bf16_t* __restrict__ Kraw,
                                              const float* __restrict__ cosT,
                                              const float* __restrict__ sinT,
                                              bf16_t* __restrict__ Qr,
                                              bf16_t* __restrict__ Kr,
                                              float* __restrict__ tok) {
    int id = blockIdx.x * 256 + threadIdx.x;      // 2048*512
    int s = id >> 9, pp = id & 511;
    int h = pp >> 5, i = pp & 31;
    int d0 = h * HD + 2 * i;
    float c  = cosT[s * 32 + i];
    float sn = sinT[s * 32 + i];
    const float scale = 0.3535533905932738f;      // 64^-0.25
    size_t base = (size_t)s * DIM + d0;

    float qa = (float)Qraw[base], qb = (float)Qraw[base + 1];
    Qr[base]     = (bf16_t)((qa * c - qb * sn) * scale);
    Qr[base + 1] = (bf16_t)((qa * sn + qb * c) * scale);

    float ka = (float)Kraw[base], kb = (float)Kraw[base + 1];
    float ra = ka * c - kb * sn;
    Kr[base]     = (bf16_t)(ra * scale);
    Kr[base + 1] = (bf16_t)((ka * sn + kb * c) * scale);
    if (i == 0) tok[h * SEQ + s] = ra;            // unscaled rotated k[...,0]
}

// ---------------- V transpose: Vt[D][S] <- V[S][D] ----------------
__global__ __launch_bounds__(256) void k_transpose(const bf16_t* __restrict__ V,
                                                   bf16_t* __restrict__ Vt) {
    __shared__ bf16_t tile[64][66];
    int t = threadIdx.x;
    int c = t & 63, r4 = t >> 6;
    int s0 = blockIdx.x * 64, d0 = blockIdx.y * 64;
#pragma unroll
    for (int i = 0; i < 16; i++) {
        int r = i * 4 + r4;
        tile[r][c] = V[(size_t)(s0 + r) * DIM + d0 + c];
    }
    __syncthreads();
#pragma unroll
    for (int i = 0; i < 16; i++) {
        int r = i * 4 + r4;   // d index within tile
        Vt[(size_t)(d0 + r) * SEQ + s0 + c] = tile[c][r];
    }
}

// ---------------- fused attention ----------------
// grid (32, 16): x = q-block (64 rows), y = head. 4 waves, each 16 q-rows.
__global__ __launch_bounds__(256) void k_attn(const bf16_t* __restrict__ Qr,
                                              const bf16_t* __restrict__ Kr,
                                              const bf16_t* __restrict__ Vt,
                                              const float* __restrict__ mask,
                                              const float* __restrict__ tok,
                                              const float* __restrict__ Zf,
                                              float* __restrict__ qk_out,
                                              bf16_t* __restrict__ wv) {
    __shared__ bf16_t plds[4][16 * 128];
    int tid = threadIdx.x, wid = tid >> 6, lane = tid & 63;
    int lrow = lane >> 4, lcol = lane & 15;
    int h = blockIdx.y;
    int q0 = blockIdx.x * 64 + wid * 16;

    float z = Zf[0];
    float zfac = fminf(fmaxf(log1pf(__expf(z)), 1e-5f), 1e-4f);

    bf16x8 aq[2];
    {
        const bf16_t* qb = Qr + (size_t)(q0 + lcol) * DIM + h * HD + lrow * 8;
        aq[0] = *(const bf16x8*)qb;
        aq[1] = *(const bf16x8*)(qb + 32);
    }

    float m[4] = {-1e30f, -1e30f, -1e30f, -1e30f};
    float l[4] = {0.f, 0.f, 0.f, 0.f};
    f32x4 acc[4] = {};
    char* wl = (char*)&plds[wid][0];
    float* qkbase = qk_out + (size_t)h * SEQ * SEQ;

    for (int kc = 0; kc < SEQ; kc += 128) {
        // ---- QK^T: 8 col-tiles of 16 ----
        f32x4 sfr[8];
#pragma unroll
        for (int ct = 0; ct < 8; ct++) {
            const bf16_t* kb = Kr + (size_t)(kc + ct * 16 + lcol) * DIM + h * HD + lrow * 8;
            bf16x8 b0 = *(const bf16x8*)kb;
            bf16x8 b1 = *(const bf16x8*)(kb + 32);
            f32x4 cacc = {};
            cacc = MFMA16(aq[0], b0, cacc);
            cacc = MFMA16(aq[1], b1, cacc);
            sfr[ct] = cacc;
        }
        // ---- zscale epilogue + qk store + row stats ----
        float p[8][4];
        float rmax[4] = {-1e30f, -1e30f, -1e30f, -1e30f};
#pragma unroll
        for (int ct = 0; ct < 8; ct++) {
            int kk = kc + ct * 16 + lcol;
            float tv = tok[h * SEQ + kk];
            float zs = (tv == 0.0f) ? zfac : 1.0f;
#pragma unroll
            for (int j = 0; j < 4; j++) {
                int row = q0 + lrow * 4 + j;
                float mk = mask[(size_t)row * SEQ + kk];
                float v = (sfr[ct][j] + mk * zs) * zs;
                qkbase[(size_t)row * SEQ + kk] = v;
                p[ct][j] = v;
                rmax[j] = fmaxf(rmax[j], v);
            }
        }
#pragma unroll
        for (int j = 0; j < 4; j++) {
            rmax[j] = fmaxf(rmax[j], __shfl_xor(rmax[j], 1));
            rmax[j] = fmaxf(rmax[j], __shfl_xor(rmax[j], 2));
            rmax[j] = fmaxf(rmax[j], __shfl_xor(rmax[j], 4));
            rmax[j] = fmaxf(rmax[j], __shfl_xor(rmax[j], 8));
        }
        float sc[4], lsum[4];
#pragma unroll
        for (int j = 0; j < 4; j++) {
            float mn = fmaxf(m[j], rmax[j]);
            sc[j] = __expf(m[j] - mn);
            m[j] = mn;
            lsum[j] = 0.f;
        }
#pragma unroll
        for (int ct = 0; ct < 8; ct++)
#pragma unroll
            for (int j = 0; j < 4; j++) {
                float e = __expf(p[ct][j] - m[j]);
                p[ct][j] = e;
                lsum[j] += e;
            }
#pragma unroll
        for (int j = 0; j < 4; j++) {
            lsum[j] += __shfl_xor(lsum[j], 1);
            lsum[j] += __shfl_xor(lsum[j], 2);
            lsum[j] += __shfl_xor(lsum[j], 4);
            lsum[j] += __shfl_xor(lsum[j], 8);
            l[j] = l[j] * sc[j] + lsum[j];
        }
#pragma unroll
        for (int ng = 0; ng < 4; ng++)
#pragma unroll
            for (int j = 0; j < 4; j++) acc[ng][j] *= sc[j];

        // ---- P -> LDS (bf16, XOR-swizzled rows) ----
        asm volatile("s_waitcnt lgkmcnt(0)" ::: "memory");  // WAR vs prev-iter reads
#pragma unroll
        for (int ct = 0; ct < 8; ct++)
#pragma unroll
            for (int j = 0; j < 4; j++) {
                int row = lrow * 4 + j;
                int addr = row * 256 + (ct * 16 + lcol) * 2;
                addr ^= (row & 7) << 4;
                *(bf16_t*)(wl + addr) = (bf16_t)p[ct][j];
            }
        asm volatile("s_waitcnt lgkmcnt(0)" ::: "memory");
        __builtin_amdgcn_sched_barrier(0);

        bf16x8 pa[4];
#pragma unroll
        for (int ks = 0; ks < 4; ks++) {
            int addr = lcol * 256 + ks * 64 + lrow * 16;
            addr ^= (lcol & 7) << 4;
            pa[ks] = *(const bf16x8*)(wl + addr);
        }
        // ---- PV ----
#pragma unroll
        for (int ks = 0; ks < 4; ks++) {
#pragma unroll
            for (int ng = 0; ng < 4; ng++) {
                const bf16_t* vb = Vt + (size_t)(h * HD + ng * 16 + lcol) * SEQ + kc + ks * 32 + lrow * 8;
                bf16x8 bv = *(const bf16x8*)vb;
                acc[ng] = MFMA16(pa[ks], bv, acc[ng]);
            }
        }
    }
    // ---- normalize + store wv (bf16) ----
#pragma unroll
    for (int ng = 0; ng < 4; ng++) {
        int col = h * HD + ng * 16 + lcol;
#pragma unroll
        for (int j = 0; j < 4; j++) {
            int row = q0 + lrow * 4 + j;
            wv[(size_t)row * DIM + col] = (bf16_t)(acc[ng][j] / l[j]);
        }
    }
}

extern "C" void kernel_launch(void* const* d_in, const int* in_sizes, int n_in,
                              void* d_out, int out_size, void* d_ws, size_t ws_size,
                              hipStream_t stream) {
    const float* x    = (const float*)d_in[0];
    const float* mask = (const float*)d_in[1];
    const float* Wq   = (const float*)d_in[2];
    const float* bq   = (const float*)d_in[3];
    const float* Wk   = (const float*)d_in[4];
    const float* Wv   = (const float*)d_in[5];
    const float* bv   = (const float*)d_in[6];
    const float* Wo   = (const float*)d_in[7];
    const float* bo   = (const float*)d_in[8];
    const float* Zf   = (const float*)d_in[9];
    const float* invf = (const float*)d_in[10];

    char* ws = (char*)d_ws;
    size_t off = 0;
    auto alloc = [&](size_t bytes) -> char* {
        char* p = ws + off;
        off += (bytes + 255) & ~(size_t)255;
        return p;
    };
    float*  cosT = (float*)alloc(65536 * 4);
    float*  sinT = (float*)alloc(65536 * 4);
    bf16_t* Xb   = (bf16_t*)alloc((size_t)SEQ * DIM * 2);
    bf16_t* Wqb  = (bf16_t*)alloc((size_t)DIM * DIM * 2);
    bf16_t* Wkb  = (bf16_t*)alloc((size_t)DIM * DIM * 2);
    bf16_t* Wvb  = (bf16_t*)alloc((size_t)DIM * DIM * 2);
    bf16_t* Wob  = (bf16_t*)alloc((size_t)DIM * DIM * 2);
    bf16_t* Qraw = (bf16_t*)alloc((size_t)SEQ * DIM * 2);
    bf16_t* Kraw = (bf16_t*)alloc((size_t)SEQ * DIM * 2);
    bf16_t* Vbuf = (bf16_t*)alloc((size_t)SEQ * DIM * 2);
    bf16_t* Qrp  = (bf16_t*)alloc((size_t)SEQ * DIM * 2);
    bf16_t* Krp  = (bf16_t*)alloc((size_t)SEQ * DIM * 2);
    bf16_t* Vt   = (bf16_t*)alloc((size_t)DIM * SEQ * 2);
    float*  tokp = (float*)alloc((size_t)NH * SEQ * 4);
    bf16_t* WVb  = (bf16_t*)alloc((size_t)SEQ * DIM * 2);

    float* outp = (float*)d_out;
    float* qkp  = outp + (size_t)SEQ * DIM;   // out is 2048*1024, then qk 16*2048*2048

    k_tables<<<256, 256, 0, stream>>>(invf, cosT, sinT);
    k_cvt<<<(SEQ * DIM / 4 + 255) / 256, 256, 0, stream>>>(x,  Xb,  SEQ * DIM / 4);
    k_cvt<<<(DIM * DIM / 4 + 255) / 256, 256, 0, stream>>>(Wq, Wqb, DIM * DIM / 4);
    k_cvt<<<(DIM * DIM / 4 + 255) / 256, 256, 0, stream>>>(Wk, Wkb, DIM * DIM / 4);
    k_cvt<<<(DIM * DIM / 4 + 255) / 256, 256, 0, stream>>>(Wv, Wvb, DIM * DIM / 4);
    k_cvt<<<(DIM * DIM / 4 + 255) / 256, 256, 0, stream>>>(Wo, Wob, DIM * DIM / 4);

    dim3 gg(SEQ / 64, DIM / 64);
    gemm_nt<<<gg, 256, 0, stream>>>(Xb, Wqb, bq,      1, Qraw, nullptr, SEQ, DIM, DIM);
    gemm_nt<<<gg, 256, 0, stream>>>(Xb, Wkb, nullptr, 0, Kraw, nullptr, SEQ, DIM, DIM);
    gemm_nt<<<gg, 256, 0, stream>>>(Xb, Wvb, bv,      1, Vbuf, nullptr, SEQ, DIM, DIM);

    k_rope<<<(SEQ * 512) / 256, 256, 0, stream>>>(Qraw, Kraw, cosT, sinT, Qrp, Krp, tokp);
    k_transpose<<<dim3(32, 16), 256, 0, stream>>>(Vbuf, Vt);

    k_attn<<<dim3(SEQ / 64, NH), 256, 0, stream>>>(Qrp, Krp, Vt, mask, tokp, Zf, qkp, WVb);

    gemm_nt<<<gg, 256, 0, stream>>>(WVb, Wob, bo, 1, nullptr, outp, SEQ, DIM, DIM);
}